// Round 5
// baseline (268.232 us; speedup 1.0000x reference)
//
#include <hip/hip_runtime.h>
#include <math.h>

typedef float f2 __attribute__((ext_vector_type(2)));
typedef float f4 __attribute__((ext_vector_type(4)));

#define NP 110592              // 48^3 voxels
#define OUT1_OFF (192 * NP)    // out0 is 192 planes, out1 follows

// grid: 648 blocks (= 3 s-slices * 216 voxel tiles), 256 threads, 2 voxels/thread
__global__ __launch_bounds__(256, 2) void recon_kernel(
    const float* __restrict__ xe,   // x_equi_shc  [2][45][NP]
    const float* __restrict__ xiv,  // x_inva_shc  [2][NP]
    const float* __restrict__ pfe,  // polar_filter_equi [2][3][5]
    const float* __restrict__ pfi,  // polar_filter_inva [2][3][1]
    const float* __restrict__ Y,    // [3][64][45]
    float* __restrict__ out)        // out0 [192][NP] ++ out1 [2][3][45][NP]
{
    __shared__ __align__(16) float Yp[64 * 48];  // this-s Y rows, c=45 holds row-sum, 46/47 zero
    __shared__ float feS[90];                    // fe[n][c] for this s
    __shared__ float gS[2];

    const int tid = threadIdx.x;
    const int bid = blockIdx.x;
    const int s   = bid % 3;   // consecutive blocks share the same voxel tile -> L3 locality on xe
    const int vb  = bid / 3;

    // ---------------- per-block setup (tiny) ----------------
    for (int i = tid; i < 64 * 45; i += 256) {
        int row = i / 45;
        int c   = i - row * 45;
        Yp[row * 48 + c] = Y[(s * 64 + row) * 45 + c];
    }
    if (tid < 128) {  // zero pads c=46,47
        int row = tid >> 1;
        Yp[row * 48 + 46 + (tid & 1)] = 0.f;
    }
    if (tid < 90) {
        int n = tid / 45;
        int c = tid - n * 45;
        int l = (c == 0) ? 0 : (c < 6) ? 1 : (c < 15) ? 2 : (c < 28) ? 3 : 4;
        feS[tid] = pfe[(n * 3 + s) * 5 + l] * sqrtf(4.f * (float)M_PI / (float)(4 * l + 1));
    }
    if (tid < 2) gS[tid] = pfi[tid * 3 + s] * sqrtf(4.f * (float)M_PI);
    __syncthreads();
    if (tid < 64) {  // c=45 channel: row sum (for the invariant term)
        float sum = 0.f;
        #pragma unroll
        for (int c = 0; c < 45; ++c) sum += Yp[tid * 48 + c];
        Yp[tid * 48 + 45] = sum;
    }
    __syncthreads();

    // ---------------- main ----------------
    const int p0 = (vb * 256 + tid) * 2;  // this thread's voxel pair

    f2 tt[48];  // t[c] for 2 voxels; statically indexed (fully unrolled loops only)

    const float* xep = xe + p0;
    float* o1 = out + OUT1_OFF + (size_t)s * 45 * NP + p0;  // n=0 plane base; n=1 is +135*NP

    #pragma unroll
    for (int c = 0; c < 45; ++c) {
        f2 x0 = *(const f2*)(xep + (size_t)c * NP);
        f2 x1 = *(const f2*)(xep + (size_t)(45 + c) * NP);
        float f0 = feS[c], f1 = feS[45 + c];
        f2 v0 = f0 * x0;
        f2 v1 = f1 * x1;
        __builtin_nontemporal_store(v0, (f2*)(o1 + (size_t)c * NP));
        __builtin_nontemporal_store(v1, (f2*)(o1 + (size_t)(135 + c) * NP));
        tt[c] = v0 + v1;
    }
    {
        f2 a0 = *(const f2*)(xiv + p0);
        f2 a1 = *(const f2*)(xiv + NP + p0);
        f2 u  = gS[0] * a0 + gS[1] * a1;
        tt[45] = u;
        f2 z = {0.f, 0.f};
        tt[46] = z;
        tt[47] = z;
    }

    // out0: 64 rows of K=48 dot products against tt
    float* o0 = out + (size_t)s * 64 * NP + p0;
    #pragma unroll 2
    for (int v = 0; v < 64; ++v) {
        const f4* yr = (const f4*)&Yp[v * 48];  // wave-uniform address -> LDS broadcast
        f2 accA = {0.f, 0.f}, accB = {0.f, 0.f};
        #pragma unroll
        for (int j = 0; j < 12; j += 2) {
            f4 ya = yr[j];
            f4 yb = yr[j + 1];
            accA += ya.x * tt[4 * j + 0];
            accA += ya.y * tt[4 * j + 1];
            accA += ya.z * tt[4 * j + 2];
            accA += ya.w * tt[4 * j + 3];
            accB += yb.x * tt[4 * j + 4];
            accB += yb.y * tt[4 * j + 5];
            accB += yb.z * tt[4 * j + 6];
            accB += yb.w * tt[4 * j + 7];
        }
        f2 acc = accA + accB;
        __builtin_nontemporal_store(acc, (f2*)(o0 + (size_t)v * NP));
    }
}

extern "C" void kernel_launch(void* const* d_in, const int* in_sizes, int n_in,
                              void* d_out, int out_size, void* d_ws, size_t ws_size,
                              hipStream_t stream) {
    const float* xe  = (const float*)d_in[0];
    const float* xiv = (const float*)d_in[1];
    const float* pfe = (const float*)d_in[2];
    const float* pfi = (const float*)d_in[3];
    const float* Y   = (const float*)d_in[4];
    float* out = (float*)d_out;
    (void)in_sizes; (void)n_in; (void)d_ws; (void)ws_size; (void)out_size;

    recon_kernel<<<dim3(648), dim3(256), 0, stream>>>(xe, xiv, pfe, pfi, Y, out);
}